// Round 10
// baseline (158.640 us; speedup 1.0000x reference)
//
#include <hip/hip_runtime.h>
#include <hip/hip_bf16.h>
#include <math.h>

constexpr int Bz = 4, Cc = 64, Hh = 128, Ww = 128, Kk = 9;
constexpr int HW = Hh * Ww;              // 16384
constexpr float EPSf = 1e-5f;
constexpr int CK = Cc * Kk;              // 576

typedef __attribute__((ext_vector_type(8))) short short8;
typedef __attribute__((ext_vector_type(4))) float f32x4;

__device__ __forceinline__ ushort f32_to_bf16(float f) {
    uint u = __float_as_uint(f);
    return (ushort)((u + 0x7fffu + ((u >> 16) & 1u)) >> 16);   // RNE
}

__device__ __forceinline__ short8 pack8(float a0, float a1, float a2, float a3,
                                        float a4, float a5, float a6, float a7) {
    union { short8 s; uint u[4]; } r;
    float2 p; __hip_bfloat162 b;
    p.x = a0; p.y = a1; b = __float22bfloat162_rn(p); r.u[0] = *reinterpret_cast<uint*>(&b);
    p.x = a2; p.y = a3; b = __float22bfloat162_rn(p); r.u[1] = *reinterpret_cast<uint*>(&b);
    p.x = a4; p.y = a5; b = __float22bfloat162_rn(p); r.u[2] = *reinterpret_cast<uint*>(&b);
    p.x = a6; p.y = a7; b = __float22bfloat162_rn(p); r.u[3] = *reinterpret_cast<uint*>(&b);
    return r.s;
}

// ---- weight fragments (deform + offset-conv) in one launch ----
__global__ void frag_kernel(const float* __restrict__ w1, const float* __restrict__ w2,
                            const float* __restrict__ ow1, const float* __restrict__ ow2,
                            ushort* __restrict__ wA1, ushort* __restrict__ wA2,
                            ushort* __restrict__ oA1, ushort* __restrict__ oA2) {
    int tid = blockIdx.x * 256 + threadIdx.x;     // 2*36864 + 2*18432 = 110592
    if (tid >= 110592) return;
    const float* src; ushort* dst; int e; int cout;
    if (tid < 36864)        { src = w1;  dst = wA1; e = tid;         cout = 64; }
    else if (tid < 73728)   { src = w2;  dst = wA2; e = tid - 36864; cout = 64; }
    else if (tid < 92160)   { src = ow1; dst = oA1; e = tid - 73728; cout = 18; }
    else                    { src = ow2; dst = oA2; e = tid - 92160; cout = 18; }
    int j = e & 7, l = (e >> 3) & 63, kk = (e >> 9) % 18, wo = e / 9216;
    int oc = wo * 16 + (l & 15);
    int kidx = kk * 32 + ((l >> 4) * 8) + j;
    int tap = kidx >> 6, c = kidx & 63;
    dst[e] = (oc < cout) ? f32_to_bf16(src[oc * CK + c * 9 + tap]) : (ushort)0;
}

// ---- NCHW fp32 -> NHWC bf16 (tiled transpose), for x only ----
__global__ __launch_bounds__(256)
void nhwc_kernel(const float* __restrict__ src, ushort* __restrict__ dst) {
    __shared__ float s_t[64][65];
    int blk = blockIdx.x;                 // Bz * (HW/64) = 1024
    int p0 = (blk & 255) * 64;
    int b = blk >> 8;
    int t = threadIdx.x;
    int tp = t & 63;
    #pragma unroll
    for (int i = 0; i < 16; i++) {
        int c = i * 4 + (t >> 6);
        s_t[c][tp] = src[((size_t)(b * 64 + c)) * HW + p0 + tp];
    }
    __syncthreads();
    #pragma unroll
    for (int i = 0; i < 16; i++) {
        int pl = i * 4 + (t >> 6);
        dst[((size_t)b * HW + p0 + pl) * 64 + tp] = f32_to_bf16(s_t[tp][pl]);
    }
}

// one deform tap: gather 4 bilinear corners (2 channel-halves), blend, 8 MFMAs
__device__ __forceinline__ void do_tap(int tap, int li, int cbyte,
                                       const char* __restrict__ xnc,
                                       const uint* s_yx, const float2* s_w2,
                                       const short8* __restrict__ wf,
                                       f32x4 (&acc)[4]) {
    int u = li * 9 + tap;
    uint yx = s_yx[u];                   // broadcast across g-lanes
    float2 w2 = s_w2[u];
    int y0 = (short)(yx & 0xffffu);
    int x0 = (short)(yx >> 16);
    float wy = w2.x, wx = w2.y;
    int y1 = y0 + 1, x1 = x0 + 1;
    bool vy0 = (unsigned)y0 < 128u, vy1 = (unsigned)y1 < 128u;
    bool vx0 = (unsigned)x0 < 128u, vx1 = (unsigned)x1 < 128u;
    int yc0 = min(max(y0, 0), 127), yc1 = min(max(y1, 0), 127);
    int xc0 = min(max(x0, 0), 127), xc1 = min(max(x1, 0), 127);
    uint a00 = (uint)(((yc0 << 7) + xc0) << 7) + cbyte;
    uint a01 = (uint)(((yc0 << 7) + xc1) << 7) + cbyte;
    uint a10 = (uint)(((yc1 << 7) + xc0) << 7) + cbyte;
    uint a11 = (uint)(((yc1 << 7) + xc1) << 7) + cbyte;
    float w00 = (vy0 && vx0) ? (1.f - wy) * (1.f - wx) : 0.f;
    float w01 = (vy0 && vx1) ? (1.f - wy) * wx : 0.f;
    float w10 = (vy1 && vx0) ? wy * (1.f - wx) : 0.f;
    float w11 = (vy1 && vx1) ? wy * wx : 0.f;
    uint4 L00 = *reinterpret_cast<const uint4*>(xnc + a00);
    uint4 L01 = *reinterpret_cast<const uint4*>(xnc + a01);
    uint4 L10 = *reinterpret_cast<const uint4*>(xnc + a10);
    uint4 L11 = *reinterpret_cast<const uint4*>(xnc + a11);
    uint4 H00 = *reinterpret_cast<const uint4*>(xnc + a00 + 64);
    uint4 H01 = *reinterpret_cast<const uint4*>(xnc + a01 + 64);
    uint4 H10 = *reinterpret_cast<const uint4*>(xnc + a10 + 64);
    uint4 H11 = *reinterpret_cast<const uint4*>(xnc + a11 + 64);
    #define LO(u) __uint_as_float((u) << 16)
    #define HI(u) __uint_as_float((u) & 0xffff0000u)
    #define BLEND(e)  (fmaf(w11, LO(L11.e), fmaf(w10, LO(L10.e), fmaf(w01, LO(L01.e), w00 * LO(L00.e)))))
    #define BLENDH(e) (fmaf(w11, HI(L11.e), fmaf(w10, HI(L10.e), fmaf(w01, HI(L01.e), w00 * HI(L00.e)))))
    #define BLEND2(e)  (fmaf(w11, LO(H11.e), fmaf(w10, LO(H10.e), fmaf(w01, LO(H01.e), w00 * LO(H00.e)))))
    #define BLEND2H(e) (fmaf(w11, HI(H11.e), fmaf(w10, HI(H10.e), fmaf(w01, HI(H01.e), w00 * HI(H00.e)))))
    short8 fa = pack8(BLEND(x), BLENDH(x), BLEND(y), BLENDH(y),
                      BLEND(z), BLENDH(z), BLEND(w), BLENDH(w));
    short8 fb = pack8(BLEND2(x), BLEND2H(x), BLEND2(y), BLEND2H(y),
                      BLEND2(z), BLEND2H(z), BLEND2(w), BLEND2H(w));
    #undef LO
    #undef HI
    #undef BLEND
    #undef BLENDH
    #undef BLEND2
    #undef BLEND2H
    #pragma unroll
    for (int tile = 0; tile < 4; tile++) {
        acc[tile] = __builtin_amdgcn_mfma_f32_16x16x32_bf16(
            wf[(tile * 18 + 2 * tap) * 64], fa, acc[tile], 0, 0, 0);
        acc[tile] = __builtin_amdgcn_mfma_f32_16x16x32_bf16(
            wf[(tile * 18 + 2 * tap + 1) * 64], fb, acc[tile], 0, 0, 0);
    }
}

// ---- fused kernel: block = 16 px, 4 waves K-split over taps {3,2,2,2} ----
// blk = ((h<<3 | b<<1 | wthi) << 2) | wtlo  ->  blk%8 = wt  ->  XCD owns one
// 16-px column slab (~1 MB across 4 samples) -> L2-resident.
__global__ __launch_bounds__(256, 6)
void deform_fused_kernel(const ushort* __restrict__ xnh, const ushort* __restrict__ wA,
                         const ushort* __restrict__ owA, const float* __restrict__ bias,
                         const float* __restrict__ obias, float* __restrict__ y,
                         float* __restrict__ part) {
    __shared__ float  off_s2[2][16][18];               // 2.3 KB
    __shared__ uint   s_yx[144];                       // 576 B
    __shared__ float2 s_w2[144];                       // 1.2 KB
    __shared__ __align__(16) float s_red[4][64][20];   // 20.5 KB (pad 20 vs 16)

    int t = threadIdx.x;
    int wv = t >> 6, lane = t & 63;
    int blk = blockIdx.x;                  // 4096
    int wtlo = blk & 3;
    int rest = blk >> 2;
    int wthi = rest & 1;
    int b = (rest >> 1) & 3;
    int h = rest >> 3;
    int wt = (wthi << 2) | wtlo;
    int w0 = wt * 16;
    int pidx = b * 1024 + h * 8 + wt;      // sample-major partial index
    int g = lane >> 4, li = lane & 15;
    const ushort* xnb = xnh + (size_t)b * HW * 64;
    const char* xnc = reinterpret_cast<const char*>(xnb);

    // ---- phase A: offset conv via MFMA; waves = (wo 0..1) x (kh 0..1) ----
    {
        int wo = wv & 1, kh = wv >> 1;
        f32x4 oacc;
        #pragma unroll
        for (int r = 0; r < 4; r++) {
            int oc = wo * 16 + g * 4 + r;
            oacc[r] = (kh == 0 && oc < 18) ? obias[oc] : 0.f;
        }
        const short8* owp = reinterpret_cast<const short8*>(owA) + (wo * 18) * 64 + lane;
        #pragma unroll
        for (int kki = 0; kki < 9; kki++) {
            int kk = kh * 9 + kki;
            int tap = kk >> 1;
            int ky = tap / 3 - 1, kx = tap - (tap / 3) * 3 - 1;
            int cb = (kk & 1) * 64 + g * 16;
            int gy = h + ky, gx = w0 + li + kx;
            bool valid = ((unsigned)gy < 128u) && ((unsigned)gx < 128u);
            short8 bf = {0, 0, 0, 0, 0, 0, 0, 0};
            if (valid)
                bf = *reinterpret_cast<const short8*>(xnc + ((((gy << 7) + gx) << 7) + cb));
            oacc = __builtin_amdgcn_mfma_f32_16x16x32_bf16(owp[kk * 64], bf, oacc, 0, 0, 0);
        }
        #pragma unroll
        for (int r = 0; r < 4; r++) {
            int oc = wo * 16 + g * 4 + r;
            if (oc < 18) off_s2[kh][li][oc] = oacc[r];
        }
    }
    __syncthreads();

    // ---- phase 0: coords for the block's 144 (px,tap) units ----
    if (t < 144) {
        int px = t / 9, k = t - px * 9;
        int ky = k / 3 - 1, kx = k - (k / 3) * 3 - 1;
        float ody = off_s2[0][px][2 * k]     + off_s2[1][px][2 * k];
        float odx = off_s2[0][px][2 * k + 1] + off_s2[1][px][2 * k + 1];
        float cy = (float)(h + ky) + ody;
        float cx = (float)(w0 + px + kx) + odx;
        float fy = floorf(cy), fx = floorf(cx);
        int y0 = (int)fy, x0 = (int)fx;
        s_yx[t] = (uint)(y0 & 0xffff) | ((uint)x0 << 16);
        float2 wv2; wv2.x = cy - fy; wv2.y = cx - fx;
        s_w2[t] = wv2;
    }
    __syncthreads();

    // ---- main: K-split deform; wave wv owns taps {0-2},{3-4},{5-6},{7-8} ----
    f32x4 acc[4];
    #pragma unroll
    for (int tile = 0; tile < 4; tile++) {
        acc[tile].x = 0.f; acc[tile].y = 0.f; acc[tile].z = 0.f; acc[tile].w = 0.f;
    }
    const short8* wf = reinterpret_cast<const short8*>(wA) + lane;
    int cbyte = g * 16;
    if (wv == 0) {
        do_tap(0, li, cbyte, xnc, s_yx, s_w2, wf, acc);
        do_tap(1, li, cbyte, xnc, s_yx, s_w2, wf, acc);
        do_tap(2, li, cbyte, xnc, s_yx, s_w2, wf, acc);
    } else if (wv == 1) {
        do_tap(3, li, cbyte, xnc, s_yx, s_w2, wf, acc);
        do_tap(4, li, cbyte, xnc, s_yx, s_w2, wf, acc);
    } else if (wv == 2) {
        do_tap(5, li, cbyte, xnc, s_yx, s_w2, wf, acc);
        do_tap(6, li, cbyte, xnc, s_yx, s_w2, wf, acc);
    } else {
        do_tap(7, li, cbyte, xnc, s_yx, s_w2, wf, acc);
        do_tap(8, li, cbyte, xnc, s_yx, s_w2, wf, acc);
    }

    // ---- write K-partials to LDS ----
    #pragma unroll
    for (int tile = 0; tile < 4; tile++)
        *reinterpret_cast<f32x4*>(&s_red[wv][lane][tile * 4]) = acc[tile];
    __syncthreads();

    // ---- merge: thread t = (tile = wv, l = lane); sum 4 K-partials ----
    {
        int tile = wv;
        f32x4 m = *reinterpret_cast<const f32x4*>(&s_red[0][lane][tile * 4]);
        m += *reinterpret_cast<const f32x4*>(&s_red[1][lane][tile * 4]);
        m += *reinterpret_cast<const f32x4*>(&s_red[2][lane][tile * 4]);
        m += *reinterpret_cast<const f32x4*>(&s_red[3][lane][tile * 4]);
        const float* bp = bias + tile * 16 + g * 4;
        m.x += bp[0]; m.y += bp[1]; m.z += bp[2]; m.w += bp[3];
        size_t ybase = ((size_t)(b * 64 + tile * 16 + g * 4)) * HW + h * Ww + w0 + li;
        y[ybase]          = m.x;
        y[ybase + HW]     = m.y;
        y[ybase + 2 * HW] = m.z;
        y[ybase + 3 * HW] = m.w;

        // GN partial for this block
        float s  = m.x + m.y + m.z + m.w;
        float s2 = m.x * m.x + m.y * m.y + m.z * m.z + m.w * m.w;
        #pragma unroll
        for (int o = 32; o > 0; o >>= 1) {
            s  += __shfl_down(s, o);
            s2 += __shfl_down(s2, o);
        }
        float* redbuf = reinterpret_cast<float*>(s_yx);   // s_yx dead now
        if (lane == 0) { redbuf[wv * 2] = s; redbuf[wv * 2 + 1] = s2; }
    }
    __syncthreads();
    if (t == 0) {
        float* redbuf = reinterpret_cast<float*>(s_yx);
        float a = 0.f, c2 = 0.f;
        #pragma unroll
        for (int i = 0; i < 4; i++) { a += redbuf[i * 2]; c2 += redbuf[i * 2 + 1]; }
        part[pidx * 2]     = a;
        part[pidx * 2 + 1] = c2;
    }
}

// shared per-block reduction of one sample's 1024 partial pairs -> (mean, rsqrt)
__device__ __forceinline__ void gn_reduce_stats(const float* __restrict__ part, int b,
                                                int t, float& m_out, float& rs_out) {
    __shared__ float ls[4][2];
    __shared__ float s_ms[2];
    int base = b * 1024 + t;
    float s  = part[base * 2]            + part[(base + 256) * 2]
             + part[(base + 512) * 2]    + part[(base + 768) * 2];
    float s2 = part[base * 2 + 1]        + part[(base + 256) * 2 + 1]
             + part[(base + 512) * 2 + 1] + part[(base + 768) * 2 + 1];
    #pragma unroll
    for (int o = 32; o > 0; o >>= 1) {
        s  += __shfl_down(s, o);
        s2 += __shfl_down(s2, o);
    }
    int wave = t >> 6, lane = t & 63;
    if (lane == 0) { ls[wave][0] = s; ls[wave][1] = s2; }
    __syncthreads();
    if (t == 0) {
        float a = 0.f, c = 0.f;
        #pragma unroll
        for (int i = 0; i < 4; i++) { a += ls[i][0]; c += ls[i][1]; }
        const float n = (float)(Cc * HW);
        float m = a / n;
        float var = c / n - m * m;
        s_ms[0] = m;
        s_ms[1] = rsqrtf(var + EPSf);
    }
    __syncthreads();
    m_out = s_ms[0];
    rs_out = s_ms[1];
}

// ---- block-1 finalize: GN-stats + normalize+ReLU+residual -> h1 + hnh ----
__global__ __launch_bounds__(256)
void gn_fin1_kernel(const float* __restrict__ y, const float* __restrict__ res,
                    const float* __restrict__ g, const float* __restrict__ be,
                    const float* __restrict__ part, float* __restrict__ h1,
                    ushort* __restrict__ hnh) {
    __shared__ float s_t[64][65];
    int blk = blockIdx.x;                 // Bz * (HW/64) = 1024
    int p0 = (blk & 255) * 64;
    int b = blk >> 8;
    int t = threadIdx.x;
    int tp = t & 63;
    float m, rs;
    gn_reduce_stats(part, b, t, m, rs);
    #pragma unroll
    for (int i = 0; i < 16; i++) {
        int c = i * 4 + (t >> 6);
        size_t idx = ((size_t)(b * 64 + c)) * HW + p0 + tp;
        float v = (y[idx] - m) * rs * g[c] + be[c];
        v = fmaxf(v, 0.f) + res[idx];
        h1[idx] = v;
        s_t[c][tp] = v;
    }
    __syncthreads();
    #pragma unroll
    for (int i = 0; i < 16; i++) {
        int pl = i * 4 + (t >> 6);
        hnh[((size_t)b * HW + p0 + pl) * 64 + tp] = f32_to_bf16(s_t[tp][pl]);
    }
}

// ---- block-2 finalize: GN-stats + normalize + ReLU + residual -> out ----
__global__ __launch_bounds__(256)
void gn_fin2_kernel(const float* __restrict__ y, const float* __restrict__ res,
                    const float* __restrict__ g, const float* __restrict__ be,
                    const float* __restrict__ part, float* __restrict__ out) {
    int idx = (blockIdx.x * 256 + threadIdx.x) * 4;   // B*C*H*W / 4 threads
    int c = (idx >> 14) & 63;
    int b = idx >> 20;
    float m, rs;
    gn_reduce_stats(part, b, threadIdx.x, m, rs);
    float gc = g[c], bc = be[c];
    float4 yv = *reinterpret_cast<const float4*>(y + idx);
    float4 rv = *reinterpret_cast<const float4*>(res + idx);
    float4 o;
    o.x = fmaxf((yv.x - m) * rs * gc + bc, 0.f) + rv.x;
    o.y = fmaxf((yv.y - m) * rs * gc + bc, 0.f) + rv.y;
    o.z = fmaxf((yv.z - m) * rs * gc + bc, 0.f) + rv.z;
    o.w = fmaxf((yv.w - m) * rs * gc + bc, 0.f) + rv.w;
    *reinterpret_cast<float4*>(out + idx) = o;
}

extern "C" void kernel_launch(void* const* d_in, const int* in_sizes, int n_in,
                              void* d_out, int out_size, void* d_ws, size_t ws_size,
                              hipStream_t stream) {
    const float* x   = (const float*)d_in[0];
    const float* w1  = (const float*)d_in[1];
    const float* b1  = (const float*)d_in[2];
    const float* ow1 = (const float*)d_in[3];
    const float* ob1 = (const float*)d_in[4];
    const float* g1  = (const float*)d_in[5];
    const float* be1 = (const float*)d_in[6];
    const float* w2  = (const float*)d_in[7];
    const float* b2  = (const float*)d_in[8];
    const float* ow2 = (const float*)d_in[9];
    const float* ob2 = (const float*)d_in[10];
    const float* g2  = (const float*)d_in[11];
    const float* be2 = (const float*)d_in[12];
    float* out = (float*)d_out;

    float* ws    = (float*)d_ws;
    float* ybuf  = ws;                                   // 4,194,304 f
    float* h1    = ybuf + (size_t)Bz * Cc * HW;          // 4,194,304 f
    ushort* xnh  = (ushort*)(h1 + (size_t)Bz * Cc * HW); // 4,194,304 bf16
    ushort* hnh  = xnh + (size_t)Bz * HW * 64;           // 4,194,304 bf16
    ushort* wA1  = hnh + (size_t)Bz * HW * 64;           // 36,864 bf16
    ushort* wA2  = wA1 + 36864;                          // 36,864 bf16
    ushort* owA1 = wA2 + 36864;                          // 18,432 bf16
    ushort* owA2 = owA1 + 18432;                         // 18,432 bf16
    float* part  = (float*)(owA2 + 18432);               // 8192 f

    frag_kernel<<<(110592 + 255) / 256, 256, 0, stream>>>(w1, w2, ow1, ow2, wA1, wA2, owA1, owA2);
    nhwc_kernel<<<Bz * (HW / 64), 256, 0, stream>>>(x, xnh);

    // block 1: fused (offset-conv + K-split deform + GN partial) -> fin1
    deform_fused_kernel<<<4096, 256, 0, stream>>>(xnh, wA1, owA1, b1, ob1, ybuf, part);
    gn_fin1_kernel<<<Bz * (HW / 64), 256, 0, stream>>>(ybuf, x, g1, be1, part, h1, hnh);

    // block 2: same, residual on h1, finalize to out
    deform_fused_kernel<<<4096, 256, 0, stream>>>(hnh, wA2, owA2, b2, ob2, ybuf, part);
    gn_fin2_kernel<<<Bz * Cc * HW / 1024, 256, 0, stream>>>(ybuf, h1, g2, be2, part, out);
}

// Round 11
// 126.193 us; speedup vs baseline: 1.2571x; 1.2571x over previous
//
#include <hip/hip_runtime.h>
#include <hip/hip_bf16.h>
#include <math.h>

constexpr int Bz = 4, Cc = 64, Hh = 128, Ww = 128, Kk = 9;
constexpr int HW = Hh * Ww;              // 16384
constexpr float EPSf = 1e-5f;
constexpr int CK = Cc * Kk;              // 576

typedef __attribute__((ext_vector_type(8))) short short8;
typedef __attribute__((ext_vector_type(4))) float f32x4;

__device__ __forceinline__ ushort f32_to_bf16(float f) {
    uint u = __float_as_uint(f);
    return (ushort)((u + 0x7fffu + ((u >> 16) & 1u)) >> 16);   // RNE
}

// ---- weight fragments (deform + offset-conv) in one launch ----
__global__ void frag_kernel(const float* __restrict__ w1, const float* __restrict__ w2,
                            const float* __restrict__ ow1, const float* __restrict__ ow2,
                            ushort* __restrict__ wA1, ushort* __restrict__ wA2,
                            ushort* __restrict__ oA1, ushort* __restrict__ oA2) {
    int tid = blockIdx.x * 256 + threadIdx.x;     // 2*36864 + 2*18432 = 110592
    if (tid >= 110592) return;
    const float* src; ushort* dst; int e; int cout;
    if (tid < 36864)        { src = w1;  dst = wA1; e = tid;         cout = 64; }
    else if (tid < 73728)   { src = w2;  dst = wA2; e = tid - 36864; cout = 64; }
    else if (tid < 92160)   { src = ow1; dst = oA1; e = tid - 73728; cout = 18; }
    else                    { src = ow2; dst = oA2; e = tid - 92160; cout = 18; }
    int j = e & 7, l = (e >> 3) & 63, kk = (e >> 9) % 18, wo = e / 9216;
    int oc = wo * 16 + (l & 15);
    int kidx = kk * 32 + ((l >> 4) * 8) + j;
    int tap = kidx >> 6, c = kidx & 63;
    dst[e] = (oc < cout) ? f32_to_bf16(src[oc * CK + c * 9 + tap]) : (ushort)0;
}

// ---- NCHW fp32 -> NHWC bf16 (tiled transpose), for x only ----
__global__ __launch_bounds__(256)
void nhwc_kernel(const float* __restrict__ src, ushort* __restrict__ dst) {
    __shared__ float s_t[64][65];
    int blk = blockIdx.x;                 // Bz * (HW/64) = 1024
    int p0 = (blk & 255) * 64;
    int b = blk >> 8;
    int t = threadIdx.x;
    int tp = t & 63;
    #pragma unroll
    for (int i = 0; i < 16; i++) {
        int c = i * 4 + (t >> 6);
        s_t[c][tp] = src[((size_t)(b * 64 + c)) * HW + p0 + tp];
    }
    __syncthreads();
    #pragma unroll
    for (int i = 0; i < 16; i++) {
        int pl = i * 4 + (t >> 6);
        dst[((size_t)b * HW + p0 + pl) * 64 + tp] = f32_to_bf16(s_t[tp][pl]);
    }
}

// ---- fused offset-conv + deformable conv + GN partial reduce ----
// block = 32 px of one (b,h) row, 512 threads; r6 structure + deep-MLP gather
__global__ __launch_bounds__(512, 4)
void deform_fused_kernel(const ushort* __restrict__ xnh, const ushort* __restrict__ wA,
                         const ushort* __restrict__ owA, const float* __restrict__ bias,
                         const float* __restrict__ obias, float* __restrict__ y,
                         float* __restrict__ part) {
    __shared__ __align__(16) ushort s_a[32 * 584];    // A[px][tap*64+c] bf16, +8 pad
    __shared__ __align__(16) uint   s_aw[32 * 9 * 8]; // per (px,tap): 4x{byteaddr,wgt}
    // off_s2 aliases s_a (phase A writes, phase 0 reads, phase 1 overwrites)
    float (*off_s2)[32][18] = reinterpret_cast<float (*)[32][18]>(s_a);

    int blk = blockIdx.x;            // Bz*Hh*(Ww/32) = 2048
    int wt = blk & 3;
    int h  = (blk >> 2) & 127;
    int b  = blk >> 9;
    int w0 = wt * 32;
    int t = threadIdx.x;
    int wv = t >> 6, lane = t & 63;
    const ushort* xnb = xnh + (size_t)b * HW * 64;

    // ---- phase A: offset conv via MFMA; all 8 waves (K split in halves) ----
    {
        int wo = wv & 1, ph = (wv >> 1) & 1, kh = wv >> 2;
        int g = lane >> 4, li = lane & 15;
        int px = ph * 16 + li;
        f32x4 oacc;
        #pragma unroll
        for (int r = 0; r < 4; r++) {
            int oc = wo * 16 + g * 4 + r;
            oacc[r] = (kh == 0 && oc < 18) ? obias[oc] : 0.f;
        }
        const short8* owp = reinterpret_cast<const short8*>(owA) + (wo * 18) * 64 + lane;
        #pragma unroll
        for (int kki = 0; kki < 9; kki++) {
            int kk = kh * 9 + kki;
            int tap = kk >> 1;
            int ky = tap / 3 - 1, kx = tap - (tap / 3) * 3 - 1;
            int c0 = (kk & 1) * 32 + g * 8;
            int gy = h + ky, gx = w0 + px + kx;
            bool valid = ((unsigned)gy < 128u) && ((unsigned)gx < 128u);
            short8 bf = {0, 0, 0, 0, 0, 0, 0, 0};
            if (valid)
                bf = *reinterpret_cast<const short8*>(&xnb[(((gy << 7) + gx) << 6) + c0]);
            short8 af = owp[kk * 64];
            oacc = __builtin_amdgcn_mfma_f32_16x16x32_bf16(af, bf, oacc, 0, 0, 0);
        }
        #pragma unroll
        for (int r = 0; r < 4; r++) {
            int oc = wo * 16 + g * 4 + r;
            if (oc < 18) off_s2[kh][px][oc] = oacc[r];
        }
    }
    __syncthreads();

    // ---- phase 0: bilinear coords -> corner byte-addrs + folded weights ----
    uint aw_l[8];
    bool has_unit = (t < 288);
    if (has_unit) {
        int px = t / 9, k = t - px * 9;
        int ky = k / 3 - 1, kx = k - (k / 3) * 3 - 1;
        float ody = off_s2[0][px][2 * k]     + off_s2[1][px][2 * k];
        float odx = off_s2[0][px][2 * k + 1] + off_s2[1][px][2 * k + 1];
        float cy = (float)(h + ky) + ody;
        float cx = (float)(w0 + px + kx) + odx;
        float fy = floorf(cy), fx = floorf(cx);
        float wy = cy - fy, wx = cx - fx;
        int y0 = (int)fy, x0 = (int)fx;
        int yy[2] = {y0, y0 + 1}; int xx[2] = {x0, x0 + 1};
        float wyv[2] = {1.f - wy, wy}; float wxv[2] = {1.f - wx, wx};
        #pragma unroll
        for (int ci = 0; ci < 2; ci++)
        #pragma unroll
        for (int cj = 0; cj < 2; cj++) {
            int yv = yy[ci], xv = xx[cj];
            bool val = ((unsigned)yv < 128u) && ((unsigned)xv < 128u);
            int ycl = min(max(yv, 0), 127), xcl = min(max(xv, 0), 127);
            int slot = ci * 2 + cj;
            aw_l[slot * 2]     = (uint)(((ycl << 7) + xcl) << 7);  // byte addr
            aw_l[slot * 2 + 1] = __float_as_uint(val ? wyv[ci] * wxv[cj] : 0.f);
        }
    }
    __syncthreads();                       // off_s2 (in s_a) now dead
    if (has_unit) {
        uint base = (uint)t * 8;
        #pragma unroll
        for (int i = 0; i < 8; i++) s_aw[base + i] = aw_l[i];
    }
    __syncthreads();

    // ---- phase 1: deep-MLP gather. Issue ALL coord reads + 20 corner loads
    //      first (explicit register arrays), then blend in order. ----
    {
        int sub = lane >> 3;               // unit slot within iteration
        int ci  = lane & 7;                // channel group
        int co  = ci << 4;                 // byte offset of channel group
        const char* xnc = reinterpret_cast<const char*>(xnb);
        char* s_ab = reinterpret_cast<char*>(s_a);

        float w00[5], w01[5], w10[5], w11[5];
        uint4 v00[5], v01[5], v10[5], v11[5];
        int   dsts[5];

        #pragma unroll
        for (int i = 0; i < 5; i++) {
            int lu = i * 8 + sub;
            int luc = lu > 35 ? 35 : lu;   // clamp (redundant work, no branch)
            int U = wv * 36 + luc;         // unit = px*9 + tap
            int px = U / 9;
            int tap = U - px * 9;
            uint4 q0 = *reinterpret_cast<const uint4*>(&s_aw[U * 8]);
            uint4 q1 = *reinterpret_cast<const uint4*>(&s_aw[U * 8 + 4]);
            w00[i] = __uint_as_float(q0.y); w01[i] = __uint_as_float(q0.w);
            w10[i] = __uint_as_float(q1.y); w11[i] = __uint_as_float(q1.w);
            v00[i] = *reinterpret_cast<const uint4*>(xnc + (q0.x + co));
            v01[i] = *reinterpret_cast<const uint4*>(xnc + (q0.z + co));
            v10[i] = *reinterpret_cast<const uint4*>(xnc + (q1.x + co));
            v11[i] = *reinterpret_cast<const uint4*>(xnc + (q1.z + co));
            dsts[i] = px * 1168 + tap * 128 + co;
        }

        #pragma unroll
        for (int i = 0; i < 5; i++) {
            int lu = i * 8 + sub;
            float W00 = w00[i], W01 = w01[i], W10 = w10[i], W11 = w11[i];
            uint4 V00 = v00[i], V01 = v01[i], V10 = v10[i], V11 = v11[i];
            float a0, a1, a2, a3, a4, a5, a6, a7;
            #define LO(u) __uint_as_float((u) << 16)
            #define HI(u) __uint_as_float((u) & 0xffff0000u)
            a0 = W00 * LO(V00.x); a1 = W00 * HI(V00.x);
            a2 = W00 * LO(V00.y); a3 = W00 * HI(V00.y);
            a4 = W00 * LO(V00.z); a5 = W00 * HI(V00.z);
            a6 = W00 * LO(V00.w); a7 = W00 * HI(V00.w);
            a0 = fmaf(W01, LO(V01.x), a0); a1 = fmaf(W01, HI(V01.x), a1);
            a2 = fmaf(W01, LO(V01.y), a2); a3 = fmaf(W01, HI(V01.y), a3);
            a4 = fmaf(W01, LO(V01.z), a4); a5 = fmaf(W01, HI(V01.z), a5);
            a6 = fmaf(W01, LO(V01.w), a6); a7 = fmaf(W01, HI(V01.w), a7);
            a0 = fmaf(W10, LO(V10.x), a0); a1 = fmaf(W10, HI(V10.x), a1);
            a2 = fmaf(W10, LO(V10.y), a2); a3 = fmaf(W10, HI(V10.y), a3);
            a4 = fmaf(W10, LO(V10.z), a4); a5 = fmaf(W10, HI(V10.z), a5);
            a6 = fmaf(W10, LO(V10.w), a6); a7 = fmaf(W10, HI(V10.w), a7);
            a0 = fmaf(W11, LO(V11.x), a0); a1 = fmaf(W11, HI(V11.x), a1);
            a2 = fmaf(W11, LO(V11.y), a2); a3 = fmaf(W11, HI(V11.y), a3);
            a4 = fmaf(W11, LO(V11.z), a4); a5 = fmaf(W11, HI(V11.z), a5);
            a6 = fmaf(W11, LO(V11.w), a6); a7 = fmaf(W11, HI(V11.w), a7);
            #undef LO
            #undef HI
            float2 p01; p01.x = a0; p01.y = a1;
            float2 p23; p23.x = a2; p23.y = a3;
            float2 p45; p45.x = a4; p45.y = a5;
            float2 p67; p67.x = a6; p67.y = a7;
            __hip_bfloat162 b01 = __float22bfloat162_rn(p01);
            __hip_bfloat162 b23 = __float22bfloat162_rn(p23);
            __hip_bfloat162 b45 = __float22bfloat162_rn(p45);
            __hip_bfloat162 b67 = __float22bfloat162_rn(p67);
            uint4 outv;
            outv.x = *reinterpret_cast<uint*>(&b01);
            outv.y = *reinterpret_cast<uint*>(&b23);
            outv.z = *reinterpret_cast<uint*>(&b45);
            outv.w = *reinterpret_cast<uint*>(&b67);
            if (lu < 36)
                *reinterpret_cast<uint4*>(s_ab + dsts[i]) = outv;
        }
    }
    __syncthreads();

    // ---- phase 2: deform MFMA. wave = (ph, wo); D[oc][px] ----
    int wo = wv & 3, ph = wv >> 2;
    int g = lane >> 4, li = lane & 15;
    f32x4 acc;
    const float* bp = bias + wo * 16 + g * 4;
    acc.x = bp[0]; acc.y = bp[1]; acc.z = bp[2]; acc.w = bp[3];
    const short8* ap = reinterpret_cast<const short8*>(wA) + (wo * 18) * 64 + lane;
    const ushort* sp = s_a + (ph * 16 + li) * 584 + g * 8;
    #pragma unroll
    for (int kk = 0; kk < 18; kk++) {
        short8 af = ap[kk * 64];                                    // weights (arg0)
        short8 bf = *reinterpret_cast<const short8*>(sp + kk * 32); // samples (arg1)
        acc = __builtin_amdgcn_mfma_f32_16x16x32_bf16(af, bf, acc, 0, 0, 0);
    }
    size_t ybase = ((size_t)(b * 64 + wo * 16 + g * 4)) * HW + h * Ww + w0 + ph * 16 + li;
    y[ybase]           = acc.x;
    y[ybase + HW]      = acc.y;
    y[ybase + 2 * HW]  = acc.z;
    y[ybase + 3 * HW]  = acc.w;

    // ---- epilogue: GN partial sums for this block's 2048 values ----
    float s  = acc.x + acc.y + acc.z + acc.w;
    float s2 = acc.x * acc.x + acc.y * acc.y + acc.z * acc.z + acc.w * acc.w;
    #pragma unroll
    for (int o = 32; o > 0; o >>= 1) {
        s  += __shfl_down(s, o);
        s2 += __shfl_down(s2, o);
    }
    float* redbuf = reinterpret_cast<float*>(s_aw);   // s_aw is dead now
    if (lane == 0) { redbuf[wv * 2] = s; redbuf[wv * 2 + 1] = s2; }
    __syncthreads();
    if (t == 0) {
        float a = 0.f, c2 = 0.f;
        #pragma unroll
        for (int i = 0; i < 8; i++) { a += redbuf[i * 2]; c2 += redbuf[i * 2 + 1]; }
        part[blk * 2]     = a;
        part[blk * 2 + 1] = c2;
    }
}

// shared per-block reduction of one sample's 512 partial pairs -> (mean, rsqrt)
__device__ __forceinline__ void gn_reduce_stats(const float* __restrict__ part, int b,
                                                int t, float& m_out, float& rs_out) {
    __shared__ float ls[4][2];
    __shared__ float s_ms[2];
    int i0 = (b * 512 + t) * 2, i1 = (b * 512 + 256 + t) * 2;
    float s  = part[i0]     + part[i1];
    float s2 = part[i0 + 1] + part[i1 + 1];
    #pragma unroll
    for (int o = 32; o > 0; o >>= 1) {
        s  += __shfl_down(s, o);
        s2 += __shfl_down(s2, o);
    }
    int wave = t >> 6, lane = t & 63;
    if (lane == 0) { ls[wave][0] = s; ls[wave][1] = s2; }
    __syncthreads();
    if (t == 0) {
        float a = 0.f, c = 0.f;
        #pragma unroll
        for (int i = 0; i < 4; i++) { a += ls[i][0]; c += ls[i][1]; }
        const float n = (float)(Cc * HW);
        float m = a / n;
        float var = c / n - m * m;
        s_ms[0] = m;
        s_ms[1] = rsqrtf(var + EPSf);
    }
    __syncthreads();
    m_out = s_ms[0];
    rs_out = s_ms[1];
}

// ---- block-1 finalize: GN-stats + normalize+ReLU+residual -> h1 + hnh ----
__global__ __launch_bounds__(256)
void gn_fin1_kernel(const float* __restrict__ y, const float* __restrict__ res,
                    const float* __restrict__ g, const float* __restrict__ be,
                    const float* __restrict__ part, float* __restrict__ h1,
                    ushort* __restrict__ hnh) {
    __shared__ float s_t[64][65];
    int blk = blockIdx.x;                 // Bz * (HW/64) = 1024
    int p0 = (blk & 255) * 64;
    int b = blk >> 8;
    int t = threadIdx.x;
    int tp = t & 63;
    float m, rs;
    gn_reduce_stats(part, b, t, m, rs);
    #pragma unroll
    for (int i = 0; i < 16; i++) {
        int c = i * 4 + (t >> 6);
        size_t idx = ((size_t)(b * 64 + c)) * HW + p0 + tp;
        float v = (y[idx] - m) * rs * g[c] + be[c];
        v = fmaxf(v, 0.f) + res[idx];
        h1[idx] = v;
        s_t[c][tp] = v;
    }
    __syncthreads();
    #pragma unroll
    for (int i = 0; i < 16; i++) {
        int pl = i * 4 + (t >> 6);
        hnh[((size_t)b * HW + p0 + pl) * 64 + tp] = f32_to_bf16(s_t[tp][pl]);
    }
}

// ---- block-2 finalize: GN-stats + normalize + ReLU + residual -> out ----
__global__ __launch_bounds__(256)
void gn_fin2_kernel(const float* __restrict__ y, const float* __restrict__ res,
                    const float* __restrict__ g, const float* __restrict__ be,
                    const float* __restrict__ part, float* __restrict__ out) {
    int idx = (blockIdx.x * 256 + threadIdx.x) * 4;   // B*C*H*W / 4 threads
    int c = (idx >> 14) & 63;
    int b = idx >> 20;
    float m, rs;
    gn_reduce_stats(part, b, threadIdx.x, m, rs);
    float gc = g[c], bc = be[c];
    float4 yv = *reinterpret_cast<const float4*>(y + idx);
    float4 rv = *reinterpret_cast<const float4*>(res + idx);
    float4 o;
    o.x = fmaxf((yv.x - m) * rs * gc + bc, 0.f) + rv.x;
    o.y = fmaxf((yv.y - m) * rs * gc + bc, 0.f) + rv.y;
    o.z = fmaxf((yv.z - m) * rs * gc + bc, 0.f) + rv.z;
    o.w = fmaxf((yv.w - m) * rs * gc + bc, 0.f) + rv.w;
    *reinterpret_cast<float4*>(out + idx) = o;
}

extern "C" void kernel_launch(void* const* d_in, const int* in_sizes, int n_in,
                              void* d_out, int out_size, void* d_ws, size_t ws_size,
                              hipStream_t stream) {
    const float* x   = (const float*)d_in[0];
    const float* w1  = (const float*)d_in[1];
    const float* b1  = (const float*)d_in[2];
    const float* ow1 = (const float*)d_in[3];
    const float* ob1 = (const float*)d_in[4];
    const float* g1  = (const float*)d_in[5];
    const float* be1 = (const float*)d_in[6];
    const float* w2  = (const float*)d_in[7];
    const float* b2  = (const float*)d_in[8];
    const float* ow2 = (const float*)d_in[9];
    const float* ob2 = (const float*)d_in[10];
    const float* g2  = (const float*)d_in[11];
    const float* be2 = (const float*)d_in[12];
    float* out = (float*)d_out;

    float* ws    = (float*)d_ws;
    float* ybuf  = ws;                                   // 4,194,304 f
    float* h1    = ybuf + (size_t)Bz * Cc * HW;          // 4,194,304 f
    ushort* xnh  = (ushort*)(h1 + (size_t)Bz * Cc * HW); // 4,194,304 bf16
    ushort* hnh  = xnh + (size_t)Bz * HW * 64;           // 4,194,304 bf16
    ushort* wA1  = hnh + (size_t)Bz * HW * 64;           // 36,864 bf16
    ushort* wA2  = wA1 + 36864;                          // 36,864 bf16
    ushort* owA1 = wA2 + 36864;                          // 18,432 bf16
    ushort* owA2 = owA1 + 18432;                         // 18,432 bf16
    float* part  = (float*)(owA2 + 18432);               // 4096 f

    frag_kernel<<<(110592 + 255) / 256, 256, 0, stream>>>(w1, w2, ow1, ow2, wA1, wA2, owA1, owA2);
    nhwc_kernel<<<Bz * (HW / 64), 256, 0, stream>>>(x, xnh);

    // block 1: offset-conv + deform_conv + GN-partial (fused) -> fin1
    deform_fused_kernel<<<Bz * Hh * (Ww / 32), 512, 0, stream>>>(xnh, wA1, owA1, b1, ob1, ybuf, part);
    gn_fin1_kernel<<<Bz * (HW / 64), 256, 0, stream>>>(ybuf, x, g1, be1, part, h1, hnh);

    // block 2: same, residual on h1, elementwise finalize to out
    deform_fused_kernel<<<Bz * Hh * (Ww / 32), 512, 0, stream>>>(hnh, wA2, owA2, b2, ob2, ybuf, part);
    gn_fin2_kernel<<<Bz * Cc * HW / 1024, 256, 0, stream>>>(ybuf, h1, g2, be2, part, out);
}

// Round 12
// 121.121 us; speedup vs baseline: 1.3098x; 1.0419x over previous
//
#include <hip/hip_runtime.h>
#include <hip/hip_bf16.h>
#include <math.h>

constexpr int Bz = 4, Cc = 64, Hh = 128, Ww = 128, Kk = 9;
constexpr int HW = Hh * Ww;              // 16384
constexpr float EPSf = 1e-5f;
constexpr int CK = Cc * Kk;              // 576

// x-tile in LDS: 5 rows x 36 cols x 128B data, pitch 144B (bank spread)
constexpr int TROWS = 5, TCOLS = 36, TPITCH = 144;

typedef __attribute__((ext_vector_type(8))) short short8;
typedef __attribute__((ext_vector_type(4))) float f32x4;

__device__ __forceinline__ ushort f32_to_bf16(float f) {
    uint u = __float_as_uint(f);
    return (ushort)((u + 0x7fffu + ((u >> 16) & 1u)) >> 16);   // RNE
}

// ---- weight fragments (deform + offset-conv) in one launch ----
__global__ void frag_kernel(const float* __restrict__ w1, const float* __restrict__ w2,
                            const float* __restrict__ ow1, const float* __restrict__ ow2,
                            ushort* __restrict__ wA1, ushort* __restrict__ wA2,
                            ushort* __restrict__ oA1, ushort* __restrict__ oA2) {
    int tid = blockIdx.x * 256 + threadIdx.x;     // 2*36864 + 2*18432 = 110592
    if (tid >= 110592) return;
    const float* src; ushort* dst; int e; int cout;
    if (tid < 36864)        { src = w1;  dst = wA1; e = tid;         cout = 64; }
    else if (tid < 73728)   { src = w2;  dst = wA2; e = tid - 36864; cout = 64; }
    else if (tid < 92160)   { src = ow1; dst = oA1; e = tid - 73728; cout = 18; }
    else                    { src = ow2; dst = oA2; e = tid - 92160; cout = 18; }
    int j = e & 7, l = (e >> 3) & 63, kk = (e >> 9) % 18, wo = e / 9216;
    int oc = wo * 16 + (l & 15);
    int kidx = kk * 32 + ((l >> 4) * 8) + j;
    int tap = kidx >> 6, c = kidx & 63;
    dst[e] = (oc < cout) ? f32_to_bf16(src[oc * CK + c * 9 + tap]) : (ushort)0;
}

// ---- NCHW fp32 -> NHWC bf16 (tiled transpose), for x only ----
__global__ __launch_bounds__(256)
void nhwc_kernel(const float* __restrict__ src, ushort* __restrict__ dst) {
    __shared__ float s_t[64][65];
    int blk = blockIdx.x;                 // Bz * (HW/64) = 1024
    int p0 = (blk & 255) * 64;
    int b = blk >> 8;
    int t = threadIdx.x;
    int tp = t & 63;
    #pragma unroll
    for (int i = 0; i < 16; i++) {
        int c = i * 4 + (t >> 6);
        s_t[c][tp] = src[((size_t)(b * 64 + c)) * HW + p0 + tp];
    }
    __syncthreads();
    #pragma unroll
    for (int i = 0; i < 16; i++) {
        int pl = i * 4 + (t >> 6);
        dst[((size_t)b * HW + p0 + pl) * 64 + tp] = f32_to_bf16(s_t[tp][pl]);
    }
}

// ---- fused offset-conv + deformable conv + GN partial reduce ----
// block = 32 px of one (b,h) row, 512 threads. r6 skeleton + LDS x-tile:
// all bilinear corners (and phase-A taps) read from a staged 5x36 px tile,
// deduplicating ~4K scattered L2 line-requests per block into ~360.
__global__ __launch_bounds__(512)
void deform_fused_kernel(const ushort* __restrict__ xnh, const ushort* __restrict__ wA,
                         const ushort* __restrict__ owA, const float* __restrict__ bias,
                         const float* __restrict__ obias, float* __restrict__ y,
                         float* __restrict__ part) {
    __shared__ __align__(16) char   s_x[TROWS * TCOLS * TPITCH];   // 25,920 B
    __shared__ __align__(16) ushort s_a[32 * 584];    // A[px][tap*64+c] bf16, +8 pad
    __shared__ __align__(16) uint   s_aw[32 * 9 * 8]; // per (px,tap): 4x{addr|flag,wgt}
    // off_s2 aliases s_a (phase A writes, phase 0 reads, phase 1 overwrites)
    float (*off_s2)[32][18] = reinterpret_cast<float (*)[32][18]>(s_a);

    int blk = blockIdx.x;            // Bz*Hh*(Ww/32) = 2048
    int wt = blk & 3;
    int h  = (blk >> 2) & 127;
    int b  = blk >> 9;
    int w0 = wt * 32;
    int t = threadIdx.x;
    int wv = t >> 6, lane = t & 63;
    const ushort* xnb = xnh + (size_t)b * HW * 64;
    const char* xnc = reinterpret_cast<const char*>(xnb);

    // ---- stage x-tile: rows h-2..h+2, cols w0-2..w0+33, zero-filled halo ----
    #pragma unroll
    for (int r = 0; r < 3; r++) {
        int e = r * 512 + t;                  // 1440 16B-chunks
        if (e < TROWS * TCOLS * 8) {
            int ch = e & 7, px = e >> 3;
            int row = px / TCOLS, col = px - row * TCOLS;
            int gy = h - 2 + row, gx = w0 - 2 + col;
            uint4 v = {0u, 0u, 0u, 0u};
            if ((unsigned)gy < 128u && (unsigned)gx < 128u)
                v = *reinterpret_cast<const uint4*>(xnc + ((((gy << 7) + gx) << 7) + ch * 16));
            *reinterpret_cast<uint4*>(&s_x[px * TPITCH + ch * 16]) = v;
        }
    }
    __syncthreads();

    // ---- phase A: offset conv via MFMA from the LDS tile; 8 waves ----
    {
        int wo = wv & 1, ph = (wv >> 1) & 1, kh = wv >> 2;
        int g = lane >> 4, li = lane & 15;
        int px = ph * 16 + li;
        f32x4 oacc;
        #pragma unroll
        for (int r = 0; r < 4; r++) {
            int oc = wo * 16 + g * 4 + r;
            oacc[r] = (kh == 0 && oc < 18) ? obias[oc] : 0.f;
        }
        const short8* owp = reinterpret_cast<const short8*>(owA) + (wo * 18) * 64 + lane;
        #pragma unroll
        for (int kki = 0; kki < 9; kki++) {
            int kk = kh * 9 + kki;
            int tap = kk >> 1;
            int ky = tap / 3 - 1, kx = tap - (tap / 3) * 3 - 1;
            int cb = (kk & 1) * 64 + g * 16;
            // tile coords: row = ky+2 (1..3), col = px+kx+2 (1..34) - always in tile;
            // out-of-image entries are zero-filled -> no validity branch.
            short8 bf = *reinterpret_cast<const short8*>(
                &s_x[((ky + 2) * TCOLS + px + kx + 2) * TPITCH + cb]);
            short8 af = owp[kk * 64];
            oacc = __builtin_amdgcn_mfma_f32_16x16x32_bf16(af, bf, oacc, 0, 0, 0);
        }
        #pragma unroll
        for (int r = 0; r < 4; r++) {
            int oc = wo * 16 + g * 4 + r;
            if (oc < 18) off_s2[kh][px][oc] = oacc[r];
        }
    }
    __syncthreads();

    // ---- phase 0: coords -> per-unit records {addr|flag, wgt} x4 ----
    // Fast path (bit31=0): addr = LDS byte offset into s_x.
    // Slow path (bit31=1): addr = global byte offset into xnb.
    uint aw_l[8];
    bool has_unit = (t < 288);
    if (has_unit) {
        int px = t / 9, k = t - px * 9;
        int ky = k / 3 - 1, kx = k - (k / 3) * 3 - 1;
        float ody = off_s2[0][px][2 * k]     + off_s2[1][px][2 * k];
        float odx = off_s2[0][px][2 * k + 1] + off_s2[1][px][2 * k + 1];
        float cy = (float)(h + ky) + ody;
        float cx = (float)(w0 + px + kx) + odx;
        float fy = floorf(cy), fx = floorf(cx);
        float wy = cy - fy, wx = cx - fx;
        int y0 = (int)fy, x0 = (int)fx;
        int y1 = y0 + 1, x1 = x0 + 1;
        bool vy0 = (unsigned)y0 < 128u, vy1 = (unsigned)y1 < 128u;
        bool vx0 = (unsigned)x0 < 128u, vx1 = (unsigned)x1 < 128u;
        int yc0 = min(max(y0, 0), 127), yc1 = min(max(y1, 0), 127);
        int xc0 = min(max(x0, 0), 127), xc1 = min(max(x1, 0), 127);
        int r0 = yc0 - (h - 2),  r1 = yc1 - (h - 2);
        int c0t = xc0 - (w0 - 2), c1t = xc1 - (w0 - 2);
        bool intile = ((unsigned)r0 < (unsigned)TROWS) && ((unsigned)r1 < (unsigned)TROWS)
                   && ((unsigned)c0t < (unsigned)TCOLS) && ((unsigned)c1t < (unsigned)TCOLS);
        uint a00, a01, a10, a11;
        if (intile) {
            a00 = (uint)((r0 * TCOLS + c0t) * TPITCH);
            a01 = (uint)((r0 * TCOLS + c1t) * TPITCH);
            a10 = (uint)((r1 * TCOLS + c0t) * TPITCH);
            a11 = (uint)((r1 * TCOLS + c1t) * TPITCH);
        } else {
            a00 = (uint)(((yc0 << 7) + xc0) << 7) | 0x80000000u;
            a01 = (uint)(((yc0 << 7) + xc1) << 7) | 0x80000000u;
            a10 = (uint)(((yc1 << 7) + xc0) << 7) | 0x80000000u;
            a11 = (uint)(((yc1 << 7) + xc1) << 7) | 0x80000000u;
        }
        aw_l[0] = a00; aw_l[1] = __float_as_uint((vy0 && vx0) ? (1.f - wy) * (1.f - wx) : 0.f);
        aw_l[2] = a01; aw_l[3] = __float_as_uint((vy0 && vx1) ? (1.f - wy) * wx : 0.f);
        aw_l[4] = a10; aw_l[5] = __float_as_uint((vy1 && vx0) ? wy * (1.f - wx) : 0.f);
        aw_l[6] = a11; aw_l[7] = __float_as_uint((vy1 && vx1) ? wy * wx : 0.f);
    }
    __syncthreads();                       // off_s2 (in s_a) now dead
    if (has_unit) {
        uint base = (uint)t * 8;
        #pragma unroll
        for (int i = 0; i < 8; i++) s_aw[base + i] = aw_l[i];
    }
    __syncthreads();

    // ---- phase 1: gather from LDS tile (fast) / global (rare slow), blend,
    //      pack bf16, store sample matrix. 8 lanes per unit, 8 ch/lane. ----
    {
        int sub = lane >> 3;               // unit slot within iteration
        int ci  = lane & 7;                // channel group
        int co  = ci << 4;                 // byte offset of channel group
        char* s_ab = reinterpret_cast<char*>(s_a);
        #pragma unroll
        for (int i = 0; i < 5; i++) {
            int lu = i * 8 + sub;
            if (lu < 36) {
                int U = wv * 36 + lu;      // unit = px*9 + tap
                int px = U / 9;
                int tap = U - px * 9;
                uint4 q0 = *reinterpret_cast<const uint4*>(&s_aw[U * 8]);
                uint4 q1 = *reinterpret_cast<const uint4*>(&s_aw[U * 8 + 4]);
                uint4 v00, v01, v10, v11;
                if (!(q0.x & 0x80000000u)) {
                    v00 = *reinterpret_cast<const uint4*>(&s_x[q0.x + co]);
                    v01 = *reinterpret_cast<const uint4*>(&s_x[q0.z + co]);
                    v10 = *reinterpret_cast<const uint4*>(&s_x[q1.x + co]);
                    v11 = *reinterpret_cast<const uint4*>(&s_x[q1.z + co]);
                } else {
                    v00 = *reinterpret_cast<const uint4*>(xnc + ((q0.x & 0x7fffffffu) + co));
                    v01 = *reinterpret_cast<const uint4*>(xnc + ((q0.z & 0x7fffffffu) + co));
                    v10 = *reinterpret_cast<const uint4*>(xnc + ((q1.x & 0x7fffffffu) + co));
                    v11 = *reinterpret_cast<const uint4*>(xnc + ((q1.z & 0x7fffffffu) + co));
                }
                float w00 = __uint_as_float(q0.y), w01 = __uint_as_float(q0.w);
                float w10 = __uint_as_float(q1.y), w11 = __uint_as_float(q1.w);
                float a0, a1, a2, a3, a4, a5, a6, a7;
                #define LO(u) __uint_as_float((u) << 16)
                #define HI(u) __uint_as_float((u) & 0xffff0000u)
                a0 = w00 * LO(v00.x); a1 = w00 * HI(v00.x);
                a2 = w00 * LO(v00.y); a3 = w00 * HI(v00.y);
                a4 = w00 * LO(v00.z); a5 = w00 * HI(v00.z);
                a6 = w00 * LO(v00.w); a7 = w00 * HI(v00.w);
                a0 = fmaf(w01, LO(v01.x), a0); a1 = fmaf(w01, HI(v01.x), a1);
                a2 = fmaf(w01, LO(v01.y), a2); a3 = fmaf(w01, HI(v01.y), a3);
                a4 = fmaf(w01, LO(v01.z), a4); a5 = fmaf(w01, HI(v01.z), a5);
                a6 = fmaf(w01, LO(v01.w), a6); a7 = fmaf(w01, HI(v01.w), a7);
                a0 = fmaf(w10, LO(v10.x), a0); a1 = fmaf(w10, HI(v10.x), a1);
                a2 = fmaf(w10, LO(v10.y), a2); a3 = fmaf(w10, HI(v10.y), a3);
                a4 = fmaf(w10, LO(v10.z), a4); a5 = fmaf(w10, HI(v10.z), a5);
                a6 = fmaf(w10, LO(v10.w), a6); a7 = fmaf(w10, HI(v10.w), a7);
                a0 = fmaf(w11, LO(v11.x), a0); a1 = fmaf(w11, HI(v11.x), a1);
                a2 = fmaf(w11, LO(v11.y), a2); a3 = fmaf(w11, HI(v11.y), a3);
                a4 = fmaf(w11, LO(v11.z), a4); a5 = fmaf(w11, HI(v11.z), a5);
                a6 = fmaf(w11, LO(v11.w), a6); a7 = fmaf(w11, HI(v11.w), a7);
                #undef LO
                #undef HI
                float2 p01; p01.x = a0; p01.y = a1;
                float2 p23; p23.x = a2; p23.y = a3;
                float2 p45; p45.x = a4; p45.y = a5;
                float2 p67; p67.x = a6; p67.y = a7;
                __hip_bfloat162 b01 = __float22bfloat162_rn(p01);
                __hip_bfloat162 b23 = __float22bfloat162_rn(p23);
                __hip_bfloat162 b45 = __float22bfloat162_rn(p45);
                __hip_bfloat162 b67 = __float22bfloat162_rn(p67);
                uint4 outv;
                outv.x = *reinterpret_cast<uint*>(&b01);
                outv.y = *reinterpret_cast<uint*>(&b23);
                outv.z = *reinterpret_cast<uint*>(&b45);
                outv.w = *reinterpret_cast<uint*>(&b67);
                *reinterpret_cast<uint4*>(s_ab + px * 1168 + tap * 128 + co) = outv;
            }
        }
    }
    __syncthreads();

    // ---- phase 2: deform MFMA. wave = (ph, wo); D[oc][px] ----
    int wo = wv & 3, ph = wv >> 2;
    int g = lane >> 4, li = lane & 15;
    f32x4 acc;
    const float* bp = bias + wo * 16 + g * 4;
    acc.x = bp[0]; acc.y = bp[1]; acc.z = bp[2]; acc.w = bp[3];
    const short8* ap = reinterpret_cast<const short8*>(wA) + (wo * 18) * 64 + lane;
    const ushort* sp = s_a + (ph * 16 + li) * 584 + g * 8;
    #pragma unroll
    for (int kk = 0; kk < 18; kk++) {
        short8 af = ap[kk * 64];                                    // weights (arg0)
        short8 bf = *reinterpret_cast<const short8*>(sp + kk * 32); // samples (arg1)
        acc = __builtin_amdgcn_mfma_f32_16x16x32_bf16(af, bf, acc, 0, 0, 0);
    }
    size_t ybase = ((size_t)(b * 64 + wo * 16 + g * 4)) * HW + h * Ww + w0 + ph * 16 + li;
    y[ybase]           = acc.x;
    y[ybase + HW]      = acc.y;
    y[ybase + 2 * HW]  = acc.z;
    y[ybase + 3 * HW]  = acc.w;

    // ---- epilogue: GN partial sums for this block's 2048 values ----
    float s  = acc.x + acc.y + acc.z + acc.w;
    float s2 = acc.x * acc.x + acc.y * acc.y + acc.z * acc.z + acc.w * acc.w;
    #pragma unroll
    for (int o = 32; o > 0; o >>= 1) {
        s  += __shfl_down(s, o);
        s2 += __shfl_down(s2, o);
    }
    float* redbuf = reinterpret_cast<float*>(s_aw);   // s_aw is dead now
    if (lane == 0) { redbuf[wv * 2] = s; redbuf[wv * 2 + 1] = s2; }
    __syncthreads();
    if (t == 0) {
        float a = 0.f, c2 = 0.f;
        #pragma unroll
        for (int i = 0; i < 8; i++) { a += redbuf[i * 2]; c2 += redbuf[i * 2 + 1]; }
        part[blk * 2]     = a;
        part[blk * 2 + 1] = c2;
    }
}

// shared per-block reduction of one sample's 512 partial pairs -> (mean, rsqrt)
__device__ __forceinline__ void gn_reduce_stats(const float* __restrict__ part, int b,
                                                int t, float& m_out, float& rs_out) {
    __shared__ float ls[4][2];
    __shared__ float s_ms[2];
    int i0 = (b * 512 + t) * 2, i1 = (b * 512 + 256 + t) * 2;
    float s  = part[i0]     + part[i1];
    float s2 = part[i0 + 1] + part[i1 + 1];
    #pragma unroll
    for (int o = 32; o > 0; o >>= 1) {
        s  += __shfl_down(s, o);
        s2 += __shfl_down(s2, o);
    }
    int wave = t >> 6, lane = t & 63;
    if (lane == 0) { ls[wave][0] = s; ls[wave][1] = s2; }
    __syncthreads();
    if (t == 0) {
        float a = 0.f, c = 0.f;
        #pragma unroll
        for (int i = 0; i < 4; i++) { a += ls[i][0]; c += ls[i][1]; }
        const float n = (float)(Cc * HW);
        float m = a / n;
        float var = c / n - m * m;
        s_ms[0] = m;
        s_ms[1] = rsqrtf(var + EPSf);
    }
    __syncthreads();
    m_out = s_ms[0];
    rs_out = s_ms[1];
}

// ---- block-1 finalize: GN-stats + normalize+ReLU+residual -> h1 + hnh ----
__global__ __launch_bounds__(256)
void gn_fin1_kernel(const float* __restrict__ y, const float* __restrict__ res,
                    const float* __restrict__ g, const float* __restrict__ be,
                    const float* __restrict__ part, float* __restrict__ h1,
                    ushort* __restrict__ hnh) {
    __shared__ float s_t[64][65];
    int blk = blockIdx.x;                 // Bz * (HW/64) = 1024
    int p0 = (blk & 255) * 64;
    int b = blk >> 8;
    int t = threadIdx.x;
    int tp = t & 63;
    float m, rs;
    gn_reduce_stats(part, b, t, m, rs);
    #pragma unroll
    for (int i = 0; i < 16; i++) {
        int c = i * 4 + (t >> 6);
        size_t idx = ((size_t)(b * 64 + c)) * HW + p0 + tp;
        float v = (y[idx] - m) * rs * g[c] + be[c];
        v = fmaxf(v, 0.f) + res[idx];
        h1[idx] = v;
        s_t[c][tp] = v;
    }
    __syncthreads();
    #pragma unroll
    for (int i = 0; i < 16; i++) {
        int pl = i * 4 + (t >> 6);
        hnh[((size_t)b * HW + p0 + pl) * 64 + tp] = f32_to_bf16(s_t[tp][pl]);
    }
}

// ---- block-2 finalize: GN-stats + normalize + ReLU + residual -> out ----
__global__ __launch_bounds__(256)
void gn_fin2_kernel(const float* __restrict__ y, const float* __restrict__ res,
                    const float* __restrict__ g, const float* __restrict__ be,
                    const float* __restrict__ part, float* __restrict__ out) {
    int idx = (blockIdx.x * 256 + threadIdx.x) * 4;   // B*C*H*W / 4 threads
    int c = (idx >> 14) & 63;
    int b = idx >> 20;
    float m, rs;
    gn_reduce_stats(part, b, threadIdx.x, m, rs);
    float gc = g[c], bc = be[c];
    float4 yv = *reinterpret_cast<const float4*>(y + idx);
    float4 rv = *reinterpret_cast<const float4*>(res + idx);
    float4 o;
    o.x = fmaxf((yv.x - m) * rs * gc + bc, 0.f) + rv.x;
    o.y = fmaxf((yv.y - m) * rs * gc + bc, 0.f) + rv.y;
    o.z = fmaxf((yv.z - m) * rs * gc + bc, 0.f) + rv.z;
    o.w = fmaxf((yv.w - m) * rs * gc + bc, 0.f) + rv.w;
    *reinterpret_cast<float4*>(out + idx) = o;
}

extern "C" void kernel_launch(void* const* d_in, const int* in_sizes, int n_in,
                              void* d_out, int out_size, void* d_ws, size_t ws_size,
                              hipStream_t stream) {
    const float* x   = (const float*)d_in[0];
    const float* w1  = (const float*)d_in[1];
    const float* b1  = (const float*)d_in[2];
    const float* ow1 = (const float*)d_in[3];
    const float* ob1 = (const float*)d_in[4];
    const float* g1  = (const float*)d_in[5];
    const float* be1 = (const float*)d_in[6];
    const float* w2  = (const float*)d_in[7];
    const float* b2  = (const float*)d_in[8];
    const float* ow2 = (const float*)d_in[9];
    const float* ob2 = (const float*)d_in[10];
    const float* g2  = (const float*)d_in[11];
    const float* be2 = (const float*)d_in[12];
    float* out = (float*)d_out;

    float* ws    = (float*)d_ws;
    float* ybuf  = ws;                                   // 4,194,304 f
    float* h1    = ybuf + (size_t)Bz * Cc * HW;          // 4,194,304 f
    ushort* xnh  = (ushort*)(h1 + (size_t)Bz * Cc * HW); // 4,194,304 bf16
    ushort* hnh  = xnh + (size_t)Bz * HW * 64;           // 4,194,304 bf16
    ushort* wA1  = hnh + (size_t)Bz * HW * 64;           // 36,864 bf16
    ushort* wA2  = wA1 + 36864;                          // 36,864 bf16
    ushort* owA1 = wA2 + 36864;                          // 18,432 bf16
    ushort* owA2 = owA1 + 18432;                         // 18,432 bf16
    float* part  = (float*)(owA2 + 18432);               // 4096 f

    frag_kernel<<<(110592 + 255) / 256, 256, 0, stream>>>(w1, w2, ow1, ow2, wA1, wA2, owA1, owA2);
    nhwc_kernel<<<Bz * (HW / 64), 256, 0, stream>>>(x, xnh);

    // block 1: offset-conv + deform_conv + GN-partial (fused) -> fin1
    deform_fused_kernel<<<Bz * Hh * (Ww / 32), 512, 0, stream>>>(xnh, wA1, owA1, b1, ob1, ybuf, part);
    gn_fin1_kernel<<<Bz * (HW / 64), 256, 0, stream>>>(ybuf, x, g1, be1, part, h1, hnh);

    // block 2: same, residual on h1, elementwise finalize to out
    deform_fused_kernel<<<Bz * Hh * (Ww / 32), 512, 0, stream>>>(hnh, wA2, owA2, b2, ob2, ybuf, part);
    gn_fin2_kernel<<<Bz * Cc * HW / 1024, 256, 0, stream>>>(ybuf, h1, g2, be2, part, out);
}

// Round 13
// 117.265 us; speedup vs baseline: 1.3528x; 1.0329x over previous
//
#include <hip/hip_runtime.h>
#include <hip/hip_bf16.h>
#include <math.h>

constexpr int Bz = 4, Cc = 64, Hh = 128, Ww = 128, Kk = 9;
constexpr int HW = Hh * Ww;              // 16384
constexpr float EPSf = 1e-5f;
constexpr int CK = Cc * Kk;              // 576

// x-tile in LDS: 5 rows x 36 cols x 128B data, pitch 144B (bank spread)
constexpr int TROWS = 5, TCOLS = 36, TPITCH = 144;

typedef __attribute__((ext_vector_type(8))) short short8;
typedef __attribute__((ext_vector_type(4))) float f32x4;

__device__ __forceinline__ ushort f32_to_bf16(float f) {
    uint u = __float_as_uint(f);
    return (ushort)((u + 0x7fffu + ((u >> 16) & 1u)) >> 16);   // RNE
}
__device__ __forceinline__ float bf16_to_f32(ushort u) {
    return __uint_as_float((uint)u << 16);
}

// ---- weight fragments (deform + offset-conv) in one launch ----
__global__ void frag_kernel(const float* __restrict__ w1, const float* __restrict__ w2,
                            const float* __restrict__ ow1, const float* __restrict__ ow2,
                            ushort* __restrict__ wA1, ushort* __restrict__ wA2,
                            ushort* __restrict__ oA1, ushort* __restrict__ oA2) {
    int tid = blockIdx.x * 256 + threadIdx.x;     // 2*36864 + 2*18432 = 110592
    if (tid >= 110592) return;
    const float* src; ushort* dst; int e; int cout;
    if (tid < 36864)        { src = w1;  dst = wA1; e = tid;         cout = 64; }
    else if (tid < 73728)   { src = w2;  dst = wA2; e = tid - 36864; cout = 64; }
    else if (tid < 92160)   { src = ow1; dst = oA1; e = tid - 73728; cout = 18; }
    else                    { src = ow2; dst = oA2; e = tid - 92160; cout = 18; }
    int j = e & 7, l = (e >> 3) & 63, kk = (e >> 9) % 18, wo = e / 9216;
    int oc = wo * 16 + (l & 15);
    int kidx = kk * 32 + ((l >> 4) * 8) + j;
    int tap = kidx >> 6, c = kidx & 63;
    dst[e] = (oc < cout) ? f32_to_bf16(src[oc * CK + c * 9 + tap]) : (ushort)0;
}

// ---- NCHW fp32 -> NHWC bf16 (tiled transpose), for x only ----
__global__ __launch_bounds__(256)
void nhwc_kernel(const float* __restrict__ src, ushort* __restrict__ dst) {
    __shared__ float s_t[64][65];
    int blk = blockIdx.x;                 // Bz * (HW/64) = 1024
    int p0 = (blk & 255) * 64;
    int b = blk >> 8;
    int t = threadIdx.x;
    int tp = t & 63;
    #pragma unroll
    for (int i = 0; i < 16; i++) {
        int c = i * 4 + (t >> 6);
        s_t[c][tp] = src[((size_t)(b * 64 + c)) * HW + p0 + tp];
    }
    __syncthreads();
    #pragma unroll
    for (int i = 0; i < 16; i++) {
        int pl = i * 4 + (t >> 6);
        dst[((size_t)b * HW + p0 + pl) * 64 + tp] = f32_to_bf16(s_t[tp][pl]);
    }
}

// ---- fused offset-conv + deformable conv + GN partial reduce ----
// block = 32 px of one (b,h) row, 512 threads; r12 structure, bf16 y output
__global__ __launch_bounds__(512)
void deform_fused_kernel(const ushort* __restrict__ xnh, const ushort* __restrict__ wA,
                         const ushort* __restrict__ owA, const float* __restrict__ bias,
                         const float* __restrict__ obias, ushort* __restrict__ y,
                         float* __restrict__ part) {
    __shared__ __align__(16) char   s_x[TROWS * TCOLS * TPITCH];   // 25,920 B
    __shared__ __align__(16) ushort s_a[32 * 584];    // A[px][tap*64+c] bf16, +8 pad
    __shared__ __align__(16) uint   s_aw[32 * 9 * 8]; // per (px,tap): 4x{addr|flag,wgt}
    // off_s2 aliases s_a (phase A writes, phase 0 reads, phase 1 overwrites)
    float (*off_s2)[32][18] = reinterpret_cast<float (*)[32][18]>(s_a);

    int blk = blockIdx.x;            // Bz*Hh*(Ww/32) = 2048
    int wt = blk & 3;
    int h  = (blk >> 2) & 127;
    int b  = blk >> 9;
    int w0 = wt * 32;
    int t = threadIdx.x;
    int wv = t >> 6, lane = t & 63;
    const ushort* xnb = xnh + (size_t)b * HW * 64;
    const char* xnc = reinterpret_cast<const char*>(xnb);

    // ---- stage x-tile: rows h-2..h+2, cols w0-2..w0+33, zero-filled halo ----
    #pragma unroll
    for (int r = 0; r < 3; r++) {
        int e = r * 512 + t;                  // 1440 16B-chunks
        if (e < TROWS * TCOLS * 8) {
            int ch = e & 7, px = e >> 3;
            int row = px / TCOLS, col = px - row * TCOLS;
            int gy = h - 2 + row, gx = w0 - 2 + col;
            uint4 v = {0u, 0u, 0u, 0u};
            if ((unsigned)gy < 128u && (unsigned)gx < 128u)
                v = *reinterpret_cast<const uint4*>(xnc + ((((gy << 7) + gx) << 7) + ch * 16));
            *reinterpret_cast<uint4*>(&s_x[px * TPITCH + ch * 16]) = v;
        }
    }
    __syncthreads();

    // ---- phase A: offset conv via MFMA from the LDS tile; 8 waves ----
    {
        int wo = wv & 1, ph = (wv >> 1) & 1, kh = wv >> 2;
        int g = lane >> 4, li = lane & 15;
        int px = ph * 16 + li;
        f32x4 oacc;
        #pragma unroll
        for (int r = 0; r < 4; r++) {
            int oc = wo * 16 + g * 4 + r;
            oacc[r] = (kh == 0 && oc < 18) ? obias[oc] : 0.f;
        }
        const short8* owp = reinterpret_cast<const short8*>(owA) + (wo * 18) * 64 + lane;
        #pragma unroll
        for (int kki = 0; kki < 9; kki++) {
            int kk = kh * 9 + kki;
            int tap = kk >> 1;
            int ky = tap / 3 - 1, kx = tap - (tap / 3) * 3 - 1;
            int cb = (kk & 1) * 64 + g * 16;
            short8 bf = *reinterpret_cast<const short8*>(
                &s_x[((ky + 2) * TCOLS + px + kx + 2) * TPITCH + cb]);
            short8 af = owp[kk * 64];
            oacc = __builtin_amdgcn_mfma_f32_16x16x32_bf16(af, bf, oacc, 0, 0, 0);
        }
        #pragma unroll
        for (int r = 0; r < 4; r++) {
            int oc = wo * 16 + g * 4 + r;
            if (oc < 18) off_s2[kh][px][oc] = oacc[r];
        }
    }
    __syncthreads();

    // ---- phase 0: coords -> per-unit records {addr|flag, wgt} x4 ----
    uint aw_l[8];
    bool has_unit = (t < 288);
    if (has_unit) {
        int px = t / 9, k = t - px * 9;
        int ky = k / 3 - 1, kx = k - (k / 3) * 3 - 1;
        float ody = off_s2[0][px][2 * k]     + off_s2[1][px][2 * k];
        float odx = off_s2[0][px][2 * k + 1] + off_s2[1][px][2 * k + 1];
        float cy = (float)(h + ky) + ody;
        float cx = (float)(w0 + px + kx) + odx;
        float fy = floorf(cy), fx = floorf(cx);
        float wy = cy - fy, wx = cx - fx;
        int y0 = (int)fy, x0 = (int)fx;
        int y1 = y0 + 1, x1 = x0 + 1;
        bool vy0 = (unsigned)y0 < 128u, vy1 = (unsigned)y1 < 128u;
        bool vx0 = (unsigned)x0 < 128u, vx1 = (unsigned)x1 < 128u;
        int yc0 = min(max(y0, 0), 127), yc1 = min(max(y1, 0), 127);
        int xc0 = min(max(x0, 0), 127), xc1 = min(max(x1, 0), 127);
        int r0 = yc0 - (h - 2),  r1 = yc1 - (h - 2);
        int c0t = xc0 - (w0 - 2), c1t = xc1 - (w0 - 2);
        bool intile = ((unsigned)r0 < (unsigned)TROWS) && ((unsigned)r1 < (unsigned)TROWS)
                   && ((unsigned)c0t < (unsigned)TCOLS) && ((unsigned)c1t < (unsigned)TCOLS);
        uint a00, a01, a10, a11;
        if (intile) {
            a00 = (uint)((r0 * TCOLS + c0t) * TPITCH);
            a01 = (uint)((r0 * TCOLS + c1t) * TPITCH);
            a10 = (uint)((r1 * TCOLS + c0t) * TPITCH);
            a11 = (uint)((r1 * TCOLS + c1t) * TPITCH);
        } else {
            a00 = (uint)(((yc0 << 7) + xc0) << 7) | 0x80000000u;
            a01 = (uint)(((yc0 << 7) + xc1) << 7) | 0x80000000u;
            a10 = (uint)(((yc1 << 7) + xc0) << 7) | 0x80000000u;
            a11 = (uint)(((yc1 << 7) + xc1) << 7) | 0x80000000u;
        }
        aw_l[0] = a00; aw_l[1] = __float_as_uint((vy0 && vx0) ? (1.f - wy) * (1.f - wx) : 0.f);
        aw_l[2] = a01; aw_l[3] = __float_as_uint((vy0 && vx1) ? (1.f - wy) * wx : 0.f);
        aw_l[4] = a10; aw_l[5] = __float_as_uint((vy1 && vx0) ? wy * (1.f - wx) : 0.f);
        aw_l[6] = a11; aw_l[7] = __float_as_uint((vy1 && vx1) ? wy * wx : 0.f);
    }
    __syncthreads();                       // off_s2 (in s_a) now dead
    if (has_unit) {
        uint base = (uint)t * 8;
        #pragma unroll
        for (int i = 0; i < 8; i++) s_aw[base + i] = aw_l[i];
    }
    __syncthreads();

    // ---- phase 1: gather from LDS tile (fast) / global (rare), blend, pack ----
    {
        int sub = lane >> 3;               // unit slot within iteration
        int ci  = lane & 7;                // channel group
        int co  = ci << 4;                 // byte offset of channel group
        char* s_ab = reinterpret_cast<char*>(s_a);
        #pragma unroll
        for (int i = 0; i < 5; i++) {
            int lu = i * 8 + sub;
            if (lu < 36) {
                int U = wv * 36 + lu;      // unit = px*9 + tap
                int px = U / 9;
                int tap = U - px * 9;
                uint4 q0 = *reinterpret_cast<const uint4*>(&s_aw[U * 8]);
                uint4 q1 = *reinterpret_cast<const uint4*>(&s_aw[U * 8 + 4]);
                uint4 v00, v01, v10, v11;
                if (!(q0.x & 0x80000000u)) {
                    v00 = *reinterpret_cast<const uint4*>(&s_x[q0.x + co]);
                    v01 = *reinterpret_cast<const uint4*>(&s_x[q0.z + co]);
                    v10 = *reinterpret_cast<const uint4*>(&s_x[q1.x + co]);
                    v11 = *reinterpret_cast<const uint4*>(&s_x[q1.z + co]);
                } else {
                    v00 = *reinterpret_cast<const uint4*>(xnc + ((q0.x & 0x7fffffffu) + co));
                    v01 = *reinterpret_cast<const uint4*>(xnc + ((q0.z & 0x7fffffffu) + co));
                    v10 = *reinterpret_cast<const uint4*>(xnc + ((q1.x & 0x7fffffffu) + co));
                    v11 = *reinterpret_cast<const uint4*>(xnc + ((q1.z & 0x7fffffffu) + co));
                }
                float w00 = __uint_as_float(q0.y), w01 = __uint_as_float(q0.w);
                float w10 = __uint_as_float(q1.y), w11 = __uint_as_float(q1.w);
                float a0, a1, a2, a3, a4, a5, a6, a7;
                #define LO(u) __uint_as_float((u) << 16)
                #define HI(u) __uint_as_float((u) & 0xffff0000u)
                a0 = w00 * LO(v00.x); a1 = w00 * HI(v00.x);
                a2 = w00 * LO(v00.y); a3 = w00 * HI(v00.y);
                a4 = w00 * LO(v00.z); a5 = w00 * HI(v00.z);
                a6 = w00 * LO(v00.w); a7 = w00 * HI(v00.w);
                a0 = fmaf(w01, LO(v01.x), a0); a1 = fmaf(w01, HI(v01.x), a1);
                a2 = fmaf(w01, LO(v01.y), a2); a3 = fmaf(w01, HI(v01.y), a3);
                a4 = fmaf(w01, LO(v01.z), a4); a5 = fmaf(w01, HI(v01.z), a5);
                a6 = fmaf(w01, LO(v01.w), a6); a7 = fmaf(w01, HI(v01.w), a7);
                a0 = fmaf(w10, LO(v10.x), a0); a1 = fmaf(w10, HI(v10.x), a1);
                a2 = fmaf(w10, LO(v10.y), a2); a3 = fmaf(w10, HI(v10.y), a3);
                a4 = fmaf(w10, LO(v10.z), a4); a5 = fmaf(w10, HI(v10.z), a5);
                a6 = fmaf(w10, LO(v10.w), a6); a7 = fmaf(w10, HI(v10.w), a7);
                a0 = fmaf(w11, LO(v11.x), a0); a1 = fmaf(w11, HI(v11.x), a1);
                a2 = fmaf(w11, LO(v11.y), a2); a3 = fmaf(w11, HI(v11.y), a3);
                a4 = fmaf(w11, LO(v11.z), a4); a5 = fmaf(w11, HI(v11.z), a5);
                a6 = fmaf(w11, LO(v11.w), a6); a7 = fmaf(w11, HI(v11.w), a7);
                #undef LO
                #undef HI
                float2 p01; p01.x = a0; p01.y = a1;
                float2 p23; p23.x = a2; p23.y = a3;
                float2 p45; p45.x = a4; p45.y = a5;
                float2 p67; p67.x = a6; p67.y = a7;
                __hip_bfloat162 b01 = __float22bfloat162_rn(p01);
                __hip_bfloat162 b23 = __float22bfloat162_rn(p23);
                __hip_bfloat162 b45 = __float22bfloat162_rn(p45);
                __hip_bfloat162 b67 = __float22bfloat162_rn(p67);
                uint4 outv;
                outv.x = *reinterpret_cast<uint*>(&b01);
                outv.y = *reinterpret_cast<uint*>(&b23);
                outv.z = *reinterpret_cast<uint*>(&b45);
                outv.w = *reinterpret_cast<uint*>(&b67);
                *reinterpret_cast<uint4*>(s_ab + px * 1168 + tap * 128 + co) = outv;
            }
        }
    }
    __syncthreads();

    // ---- phase 2: deform MFMA. wave = (ph, wo); D[oc][px]; bf16 store ----
    int wo = wv & 3, ph = wv >> 2;
    int g = lane >> 4, li = lane & 15;
    f32x4 acc;
    const float* bp = bias + wo * 16 + g * 4;
    acc.x = bp[0]; acc.y = bp[1]; acc.z = bp[2]; acc.w = bp[3];
    const short8* ap = reinterpret_cast<const short8*>(wA) + (wo * 18) * 64 + lane;
    const ushort* sp = s_a + (ph * 16 + li) * 584 + g * 8;
    #pragma unroll
    for (int kk = 0; kk < 18; kk++) {
        short8 af = ap[kk * 64];                                    // weights (arg0)
        short8 bf = *reinterpret_cast<const short8*>(sp + kk * 32); // samples (arg1)
        acc = __builtin_amdgcn_mfma_f32_16x16x32_bf16(af, bf, acc, 0, 0, 0);
    }
    size_t ybase = ((size_t)(b * 64 + wo * 16 + g * 4)) * HW + h * Ww + w0 + ph * 16 + li;
    y[ybase]           = f32_to_bf16(acc.x);
    y[ybase + HW]      = f32_to_bf16(acc.y);
    y[ybase + 2 * HW]  = f32_to_bf16(acc.z);
    y[ybase + 3 * HW]  = f32_to_bf16(acc.w);

    // ---- epilogue: GN partial sums (from f32 accumulators) ----
    float s  = acc.x + acc.y + acc.z + acc.w;
    float s2 = acc.x * acc.x + acc.y * acc.y + acc.z * acc.z + acc.w * acc.w;
    #pragma unroll
    for (int o = 32; o > 0; o >>= 1) {
        s  += __shfl_down(s, o);
        s2 += __shfl_down(s2, o);
    }
    float* redbuf = reinterpret_cast<float*>(s_aw);   // s_aw is dead now
    if (lane == 0) { redbuf[wv * 2] = s; redbuf[wv * 2 + 1] = s2; }
    __syncthreads();
    if (t == 0) {
        float a = 0.f, c2 = 0.f;
        #pragma unroll
        for (int i = 0; i < 8; i++) { a += redbuf[i * 2]; c2 += redbuf[i * 2 + 1]; }
        part[blk * 2]     = a;
        part[blk * 2 + 1] = c2;
    }
}

// shared per-block reduction of one sample's 512 partial pairs -> (mean, rsqrt)
__device__ __forceinline__ void gn_reduce_stats(const float* __restrict__ part, int b,
                                                int t, float& m_out, float& rs_out) {
    __shared__ float ls[4][2];
    __shared__ float s_ms[2];
    int i0 = (b * 512 + t) * 2, i1 = (b * 512 + 256 + t) * 2;
    float s  = part[i0]     + part[i1];
    float s2 = part[i0 + 1] + part[i1 + 1];
    #pragma unroll
    for (int o = 32; o > 0; o >>= 1) {
        s  += __shfl_down(s, o);
        s2 += __shfl_down(s2, o);
    }
    int wave = t >> 6, lane = t & 63;
    if (lane == 0) { ls[wave][0] = s; ls[wave][1] = s2; }
    __syncthreads();
    if (t == 0) {
        float a = 0.f, c = 0.f;
        #pragma unroll
        for (int i = 0; i < 4; i++) { a += ls[i][0]; c += ls[i][1]; }
        const float n = (float)(Cc * HW);
        float m = a / n;
        float var = c / n - m * m;
        s_ms[0] = m;
        s_ms[1] = rsqrtf(var + EPSf);
    }
    __syncthreads();
    m_out = s_ms[0];
    rs_out = s_ms[1];
}

// ---- block-1 finalize: GN-stats + normalize+ReLU+residual -> h1 + hnh ----
__global__ __launch_bounds__(256)
void gn_fin1_kernel(const ushort* __restrict__ y, const float* __restrict__ res,
                    const float* __restrict__ g, const float* __restrict__ be,
                    const float* __restrict__ part, float* __restrict__ h1,
                    ushort* __restrict__ hnh) {
    __shared__ float s_t[64][65];
    int blk = blockIdx.x;                 // Bz * (HW/64) = 1024
    int p0 = (blk & 255) * 64;
    int b = blk >> 8;
    int t = threadIdx.x;
    int tp = t & 63;
    float m, rs;
    gn_reduce_stats(part, b, t, m, rs);
    #pragma unroll
    for (int i = 0; i < 16; i++) {
        int c = i * 4 + (t >> 6);
        size_t idx = ((size_t)(b * 64 + c)) * HW + p0 + tp;
        float v = (bf16_to_f32(y[idx]) - m) * rs * g[c] + be[c];
        v = fmaxf(v, 0.f) + res[idx];
        h1[idx] = v;
        s_t[c][tp] = v;
    }
    __syncthreads();
    #pragma unroll
    for (int i = 0; i < 16; i++) {
        int pl = i * 4 + (t >> 6);
        hnh[((size_t)b * HW + p0 + pl) * 64 + tp] = f32_to_bf16(s_t[tp][pl]);
    }
}

// ---- block-2 finalize: GN-stats + normalize + ReLU + residual -> out ----
__global__ __launch_bounds__(256)
void gn_fin2_kernel(const ushort* __restrict__ y, const float* __restrict__ res,
                    const float* __restrict__ g, const float* __restrict__ be,
                    const float* __restrict__ part, float* __restrict__ out) {
    int idx = (blockIdx.x * 256 + threadIdx.x) * 4;   // B*C*H*W / 4 threads
    int c = (idx >> 14) & 63;
    int b = idx >> 20;
    float m, rs;
    gn_reduce_stats(part, b, threadIdx.x, m, rs);
    float gc = g[c], bc = be[c];
    ushort4 yv = *reinterpret_cast<const ushort4*>(y + idx);
    float4 rv = *reinterpret_cast<const float4*>(res + idx);
    float4 o;
    o.x = fmaxf((bf16_to_f32(yv.x) - m) * rs * gc + bc, 0.f) + rv.x;
    o.y = fmaxf((bf16_to_f32(yv.y) - m) * rs * gc + bc, 0.f) + rv.y;
    o.z = fmaxf((bf16_to_f32(yv.z) - m) * rs * gc + bc, 0.f) + rv.z;
    o.w = fmaxf((bf16_to_f32(yv.w) - m) * rs * gc + bc, 0.f) + rv.w;
    *reinterpret_cast<float4*>(out + idx) = o;
}

extern "C" void kernel_launch(void* const* d_in, const int* in_sizes, int n_in,
                              void* d_out, int out_size, void* d_ws, size_t ws_size,
                              hipStream_t stream) {
    const float* x   = (const float*)d_in[0];
    const float* w1  = (const float*)d_in[1];
    const float* b1  = (const float*)d_in[2];
    const float* ow1 = (const float*)d_in[3];
    const float* ob1 = (const float*)d_in[4];
    const float* g1  = (const float*)d_in[5];
    const float* be1 = (const float*)d_in[6];
    const float* w2  = (const float*)d_in[7];
    const float* b2  = (const float*)d_in[8];
    const float* ow2 = (const float*)d_in[9];
    const float* ob2 = (const float*)d_in[10];
    const float* g2  = (const float*)d_in[11];
    const float* be2 = (const float*)d_in[12];
    float* out = (float*)d_out;

    ushort* ybuf = (ushort*)d_ws;                        // 4,194,304 bf16 (8 MB)
    float* h1    = (float*)(ybuf + (size_t)Bz * Cc * HW);// 4,194,304 f
    ushort* xnh  = (ushort*)(h1 + (size_t)Bz * Cc * HW); // 4,194,304 bf16
    ushort* hnh  = xnh + (size_t)Bz * HW * 64;           // 4,194,304 bf16
    ushort* wA1  = hnh + (size_t)Bz * HW * 64;           // 36,864 bf16
    ushort* wA2  = wA1 + 36864;                          // 36,864 bf16
    ushort* owA1 = wA2 + 36864;                          // 18,432 bf16
    ushort* owA2 = owA1 + 18432;                         // 18,432 bf16
    float* part  = (float*)(owA2 + 18432);               // 4096 f

    frag_kernel<<<(110592 + 255) / 256, 256, 0, stream>>>(w1, w2, ow1, ow2, wA1, wA2, owA1, owA2);
    nhwc_kernel<<<Bz * (HW / 64), 256, 0, stream>>>(x, xnh);

    // block 1: offset-conv + deform_conv + GN-partial (fused) -> fin1
    deform_fused_kernel<<<Bz * Hh * (Ww / 32), 512, 0, stream>>>(xnh, wA1, owA1, b1, ob1, ybuf, part);
    gn_fin1_kernel<<<Bz * (HW / 64), 256, 0, stream>>>(ybuf, x, g1, be1, part, h1, hnh);

    // block 2: same, residual on h1, elementwise finalize to out
    deform_fused_kernel<<<Bz * Hh * (Ww / 32), 512, 0, stream>>>(hnh, wA2, owA2, b2, ob2, ybuf, part);
    gn_fin2_kernel<<<Bz * Cc * HW / 1024, 256, 0, stream>>>(ybuf, h1, g2, be2, part, out);
}